// Round 5
// baseline (1161.247 us; speedup 1.0000x reference)
//
#include <hip/hip_runtime.h>

// SchNet forward, MI355X. B=8,A=256,N=255,NB=NF=128,NG=25,NI=3,CUTOFF=5.
// R5: no weight staging (L1-resident global frags), 32KB LDS -> 4 blocks/CU,
//     4 waves/atom (8 waves/SIMD, single batch), molecule==XCD locality.

#define NATOM 2048   // B*A
#define NNBR  255

typedef __attribute__((ext_vector_type(8))) short bf16x8;  // 8 bf16 = 4 VGPR
typedef __attribute__((ext_vector_type(4))) float f32x4;

__device__ __forceinline__ unsigned short f2bf(float x){
  unsigned int u = __float_as_uint(x);
  u += 0x7fffu + ((u >> 16) & 1u);            // round-to-nearest-even
  return (unsigned short)(u >> 16);
}

// ssp(x) = softplus(x) - ln2 = ln(0.5*e^x + 0.5)
__device__ __forceinline__ float sspf(float x){
  return __logf(fmaf(0.5f, __expf(x), 0.5f));
}

// ---------- geometry + deterministic compaction of active (S!=0) neighbors
__global__ void k_prep(const float* __restrict__ pos, const int* __restrict__ nbr,
                       const float* __restrict__ mask,
                       float* __restrict__ r_c, float* __restrict__ S_c,
                       int* __restrict__ nb_c, int* __restrict__ nact_g){
  __shared__ int wcnt[4];
  const int n = threadIdx.x;
  const int atom = (blockIdx.x & 7)*256 + (blockIdx.x >> 3);   // mol == XCD
  const int molBase = atom & ~255;
  const int wid = n >> 6, lane = n & 63;
  float r = 0.f, S = 0.f; int nb = 0;
  if (n < NNBR){
    nb = nbr[atom*NNBR + n];
    const float ax = pos[atom*3+0], ay = pos[atom*3+1], az = pos[atom*3+2];
    const int pi = (molBase + nb)*3;
    const float dx = pos[pi+0]-ax, dy = pos[pi+1]-ay, dz = pos[pi+2]-az;
    r = sqrtf(dx*dx + dy*dy + dz*dz + 1e-12f);
    const float m = mask[atom*NNBR + n];
    r *= m;
    const float C = (r < 5.0f) ? 0.5f*(__cosf(r*0.6283185307179586f)+1.0f) : 0.f;
    S = C * m;
  }
  r_c[atom*256 + n] = 0.f; S_c[atom*256 + n] = 0.f; nb_c[atom*256 + n] = 0;
  const unsigned long long b = __ballot(S != 0.f);
  const int rank = __popcll(b & ((1ull << lane) - 1ull));
  if (lane == 0) wcnt[wid] = __popcll(b);
  __syncthreads();
  int off = 0;
  for (int w = 0; w < 4; ++w) if (w < wid) off += wcnt[w];
  if (S != 0.f){
    const int slot = off + rank;
    r_c[atom*256 + slot] = r; S_c[atom*256 + slot] = S; nb_c[atom*256 + slot] = nb;
  }
  if (n == 0) nact_g[atom] = wcnt[0] + wcnt[1] + wcnt[2] + wcnt[3];
}

// ---- fw1/fw2 -> MFMA B-frags (bf16), parallel + coalesced.
__global__ void k_prepw(const float* __restrict__ fw1, const float* __restrict__ fw2,
                        unsigned short* __restrict__ b1f, unsigned short* __restrict__ b2f){
  const int i = blockIdx.x / 10, part = blockIdx.x % 10, tid = threadIdx.x;
  if (part < 2){
    const int e = part*256 + tid;                    // entry in [0,512)
    const float* w1 = fw1 + i*25*128;
    unsigned short* o1 = b1f + i*512*8;
    const int n = e >> 6, l = e & 63, khi = l >> 4, llo = l & 15;
    unsigned short v[8];
    #pragma unroll
    for (int j = 0; j < 8; ++j){
      const int g = khi*8 + j;
      v[j] = f2bf((g < 25) ? w1[g*128 + n*16 + llo] : 0.f);
    }
    *(float4*)(o1 + e*8) = *(float4*)v;
  } else {
    const int e = (part - 2)*256 + tid;              // entry in [0,2048)
    const float* w2 = fw2 + i*128*128;
    unsigned short* o2 = b2f + i*2048*8;
    const int frag = e >> 6, l = e & 63;
    const int k0 = frag >> 3, n = frag & 7, khi = l >> 4, llo = l & 15;
    unsigned short v[8];
    #pragma unroll
    for (int j = 0; j < 8; ++j){
      const int k = k0*32 + khi*8 + j;
      v[j] = f2bf(w2[k*128 + n*16 + llo]);
    }
    *(float4*)(o2 + e*8) = *(float4*)v;
  }
}

// ------------------------------------------ x = emb[Z]; y = x @ in2f_0
__global__ void k_init(const int* __restrict__ Z, const float* __restrict__ emb,
                       const float* __restrict__ in2f0,
                       float* __restrict__ x, float* __restrict__ y){
  __shared__ float xs[128];
  const int t = threadIdx.x;
  const int atom = (blockIdx.x & 7)*256 + (blockIdx.x >> 3);
  const float v = emb[Z[atom]*128 + t];
  x[atom*128 + t] = v; xs[t] = v;
  __syncthreads();
  float acc[8] = {0.f,0.f,0.f,0.f,0.f,0.f,0.f,0.f};
  #pragma unroll 4
  for (int d0 = 0; d0 < 128; d0 += 8)
    #pragma unroll
    for (int u = 0; u < 8; ++u)
      acc[u] = fmaf(xs[d0+u], in2f0[(d0+u)*128 + t], acc[u]);
  y[atom*128 + t] = ((acc[0]+acc[1])+(acc[2]+acc[3]))+((acc[4]+acc[5])+(acc[6]+acc[7]));
}

// ---- x += ssp(agg@f2out+b)@dense+b ; then y = x @ in2f_next (if given)
__global__ void k_mlp(const float* __restrict__ agg,
                      const float* __restrict__ f2w, const float* __restrict__ f2b,
                      const float* __restrict__ dw, const float* __restrict__ db,
                      const float* __restrict__ in2f_next,
                      float* __restrict__ x, float* __restrict__ y){
  __shared__ float aggL[128], v1[128], xs[128];
  const int t = threadIdx.x;
  const int atom = (blockIdx.x & 7)*256 + (blockIdx.x >> 3);
  aggL[t] = agg[atom*128 + t];
  __syncthreads();
  float a[8] = {0.f,0.f,0.f,0.f,0.f,0.f,0.f,0.f};
  #pragma unroll 4
  for (int d0 = 0; d0 < 128; d0 += 8)
    #pragma unroll
    for (int u = 0; u < 8; ++u)
      a[u] = fmaf(aggL[d0+u], f2w[(d0+u)*128 + t], a[u]);
  v1[t] = sspf(((a[0]+a[1])+(a[2]+a[3]))+((a[4]+a[5])+(a[6]+a[7])) + f2b[t]);
  __syncthreads();
  float b[8] = {0.f,0.f,0.f,0.f,0.f,0.f,0.f,0.f};
  #pragma unroll 4
  for (int d0 = 0; d0 < 128; d0 += 8)
    #pragma unroll
    for (int u = 0; u < 8; ++u)
      b[u] = fmaf(v1[d0+u], dw[(d0+u)*128 + t], b[u]);
  const float xn = x[atom*128 + t] +
      (((b[0]+b[1])+(b[2]+b[3]))+((b[4]+b[5])+(b[6]+b[7]))) + db[t];
  x[atom*128 + t] = xn;
  if (in2f_next){
    xs[t] = xn;
    __syncthreads();
    float yv[8] = {0.f,0.f,0.f,0.f,0.f,0.f,0.f,0.f};
    #pragma unroll 4
    for (int d0 = 0; d0 < 128; d0 += 8)
      #pragma unroll
      for (int u = 0; u < 8; ++u)
        yv[u] = fmaf(xs[d0+u], in2f_next[(d0+u)*128 + t], yv[u]);
    y[atom*128 + t] = ((yv[0]+yv[1])+(yv[2]+yv[3]))+((yv[4]+yv[5])+(yv[6]+yv[7]));
  }
}

// ---- filter net (MFMA) + cfconv agg: 2 atoms/block, 4 waves/atom, no staging
__global__ __launch_bounds__(512, 8) void k_pairs(
    const float* __restrict__ r_c, const float* __restrict__ S_c,
    const int* __restrict__ nb_c, const int* __restrict__ nact_g,
    const float* __restrict__ y,
    const unsigned short* __restrict__ b1f, const unsigned short* __restrict__ b2f,
    const float* __restrict__ fb1, const float* __restrict__ fb2,
    float* __restrict__ agg){
  // LDS 32KB: 8 waves x 4KB wave-local H buffer (reused as 128-f32 red area)
  __shared__ __align__(16) char smem[32768];
  const int tid = threadIdx.x;
  const int wid = tid >> 6, lane = tid & 63, lhi = lane >> 4, llo = lane & 15;
  const int sub = wid & 3, ai = wid >> 2;          // 4 waves per atom
  const int mol = blockIdx.x & 7;                  // molecule == XCD
  const int atom = mol*256 + (blockIdx.x >> 3)*2 + ai, molBase = mol*256;
  char* Hw = smem + wid*4096;

  float b1b[8], b2b[8];
  #pragma unroll
  for (int n = 0; n < 8; ++n){ b1b[n] = fb1[n*16 + llo]; b2b[n] = fb2[n*16 + llo]; }

  const int nact = nact_g[atom];
  const int ntiles = (nact + 15) >> 4;

  float aggp[8];
  #pragma unroll
  for (int n = 0; n < 8; ++n) aggp[n] = 0.f;

  const float STEP = 5.0f/24.0f;
  const float GC   = -11.52f;              // -0.5/STEP^2

  for (int t = sub; t < ntiles; t += 4){
    const int row0 = t*16;
    // A1 fragment in-register: f[row0+llo][g=8*lhi+jj]
    const float r = r_c[atom*256 + row0 + llo];
    bf16x8 a1;
    #pragma unroll
    for (int jj = 0; jj < 8; ++jj){
      const int g = lhi*8 + jj;
      float v = 0.f;
      if (g < 25){ const float d = r - (float)g*STEP; v = __expf(GC*d*d); }
      a1[jj] = (short)f2bf(v);
    }
    // GEMM1 (2 halves of 4 frags to bound VGPR): H = f @ fw1 + b1 (bias via C)
    #pragma unroll
    for (int half = 0; half < 2; ++half){
      f32x4 h[4];
      #pragma unroll
      for (int q = 0; q < 4; ++q){
        const int n = half*4 + q;
        const bf16x8 b1v = *(const bf16x8*)(b1f + (n*64 + lane)*8);
        const f32x4 cin = {b1b[n], b1b[n], b1b[n], b1b[n]};
        h[q] = __builtin_amdgcn_mfma_f32_16x16x32_bf16(a1, b1v, cin, 0, 0, 0);
      }
      // ssp -> bf16 into wave-local swizzled LDS (transpose for GEMM2 A-frag)
      #pragma unroll
      for (int q = 0; q < 4; ++q){
        const int n = half*4 + q;
        #pragma unroll
        for (int j = 0; j < 4; ++j){
          const int lrow = 4*lhi + j;
          const float hv = sspf(h[q][j]);
          const int boff = (lrow*256 + (n*16 + llo)*2) ^ ((lrow & 7) << 4);
          *(unsigned short*)(Hw + boff) = f2bf(hv);
        }
      }
    }
    // GEMM2: W = H @ fw2 + b2 (bias via C), K=128 in 4 steps, B from global/L1
    f32x4 acc[8];
    #pragma unroll
    for (int n = 0; n < 8; ++n) acc[n] = f32x4{b2b[n], b2b[n], b2b[n], b2b[n]};
    #pragma unroll
    for (int k0 = 0; k0 < 4; ++k0){
      const int boff = (llo*256 + k0*64 + lhi*16) ^ ((llo & 7) << 4);
      const bf16x8 a2 = *(const bf16x8*)(Hw + boff);
      #pragma unroll
      for (int n = 0; n < 8; ++n){
        const bf16x8 b2v = *(const bf16x8*)(b2f + ((k0*8 + n)*64 + lane)*8);
        acc[n] = __builtin_amdgcn_mfma_f32_16x16x32_bf16(a2, b2v, acc[n], 0, 0, 0);
      }
    }
    // aggregate: agg[f] += W*S * y[nbr]
    #pragma unroll
    for (int j = 0; j < 4; ++j){
      const int grow = row0 + 4*lhi + j;
      const float S = S_c[atom*256 + grow];
      const float* yrow = y + (molBase + nb_c[atom*256 + grow])*128;
      #pragma unroll
      for (int n = 0; n < 8; ++n)
        aggp[n] = fmaf(acc[n][j] * S, yrow[n*16 + llo], aggp[n]);
    }
  }

  // wave-local reduction across the 4 row-groups
  #pragma unroll
  for (int n = 0; n < 8; ++n){
    aggp[n] += __shfl_xor(aggp[n], 16);
    aggp[n] += __shfl_xor(aggp[n], 32);
  }
  // cross-wave (4 waves/atom) via per-wave LDS areas
  float* red = (float*)Hw;
  if (lane < 16){
    #pragma unroll
    for (int n = 0; n < 8; ++n) red[n*16 + lane] = aggp[n];
  }
  __syncthreads();
  if (sub == 0 && lane < 16){
    #pragma unroll
    for (int n = 0; n < 8; ++n){
      float s = 0.f;
      #pragma unroll
      for (int k = 0; k < 4; ++k)
        s += ((const float*)(smem + (ai*4 + k)*4096))[n*16 + lane];
      agg[atom*128 + n*16 + lane] = s;
    }
  }
}

// ---------------------------------------------------------------------------
extern "C" void kernel_launch(void* const* d_in, const int* in_sizes, int n_in,
                              void* d_out, int out_size, void* d_ws, size_t ws_size,
                              hipStream_t stream){
  const int*   Z    = (const int*)  d_in[0];
  const float* pos  = (const float*)d_in[1];
  const int*   nbr  = (const int*)  d_in[2];
  const float* mask = (const float*)d_in[3];
  const float* emb  = (const float*)d_in[4];
  const float* fw1  = (const float*)d_in[5];
  const float* fb1  = (const float*)d_in[6];
  const float* fw2  = (const float*)d_in[7];
  const float* fb2  = (const float*)d_in[8];
  const float* in2f = (const float*)d_in[9];
  const float* f2w  = (const float*)d_in[10];
  const float* f2b  = (const float*)d_in[11];
  const float* dw   = (const float*)d_in[12];
  const float* db   = (const float*)d_in[13];
  float* x = (float*)d_out;

  char* ws = (char*)d_ws;
  float* y    = (float*)ws;                               // 1MB
  float* agg  = (float*)(ws + 1*1024*1024);               // 1MB
  float* r_c  = (float*)(ws + 2*1024*1024);               // 2MB
  float* S_c  = (float*)(ws + 4*1024*1024);               // 2MB
  int*   nb_c = (int*)  (ws + 6*1024*1024);               // 2MB
  int*   nact = (int*)  (ws + 8*1024*1024);               // 8KB
  unsigned short* b1f = (unsigned short*)(ws + 8*1024*1024 + 16*1024);   // 24KB
  unsigned short* b2f = (unsigned short*)(ws + 8*1024*1024 + 64*1024);   // 96KB

  k_prepw<<<30,    256, 0, stream>>>(fw1, fw2, b1f, b2f);
  k_prep <<<NATOM, 256, 0, stream>>>(pos, nbr, mask, r_c, S_c, nb_c, nact);
  k_init <<<NATOM, 128, 0, stream>>>(Z, emb, in2f, x, y);
  for (int i = 0; i < 3; ++i){
    k_pairs<<<NATOM/2, 512, 0, stream>>>(r_c, S_c, nb_c, nact, y,
        b1f + i*512*8, b2f + i*2048*8, fb1 + i*128, fb2 + i*128, agg);
    k_mlp  <<<NATOM, 128, 0, stream>>>(agg,
        f2w + i*16384, f2b + i*128, dw + i*16384, db + i*128,
        (i < 2) ? (in2f + (i+1)*16384) : nullptr, x, y);
  }
}

// Round 6
// 616.046 us; speedup vs baseline: 1.8850x; 1.8850x over previous
//
#include <hip/hip_runtime.h>

// SchNet forward, MI355X. B=8,A=256,N=255,NB=NF=128,NG=25,NI=3,CUTOFF=5.
// R6: wave-per-atom k_pairs, no weight staging (L1-hot global frags),
//     no barriers, 256thr/4-wave blocks, launch_bounds(256,4) -> no spill.

#define NATOM 2048   // B*A
#define NNBR  255

typedef __attribute__((ext_vector_type(8))) short bf16x8;  // 8 bf16 = 4 VGPR
typedef __attribute__((ext_vector_type(4))) float f32x4;

__device__ __forceinline__ unsigned short f2bf(float x){
  unsigned int u = __float_as_uint(x);
  u += 0x7fffu + ((u >> 16) & 1u);            // round-to-nearest-even
  return (unsigned short)(u >> 16);
}

// ssp(x) = softplus(x) - ln2 = ln(0.5*e^x + 0.5)
__device__ __forceinline__ float sspf(float x){
  return __logf(fmaf(0.5f, __expf(x), 0.5f));
}

// ---------- geometry + deterministic compaction of active (S!=0) neighbors
__global__ void k_prep(const float* __restrict__ pos, const int* __restrict__ nbr,
                       const float* __restrict__ mask,
                       float* __restrict__ r_c, float* __restrict__ S_c,
                       int* __restrict__ nb_c, int* __restrict__ nact_g){
  __shared__ int wcnt[4];
  const int n = threadIdx.x;
  const int atom = (blockIdx.x & 7)*256 + (blockIdx.x >> 3);   // mol == XCD
  const int molBase = atom & ~255;
  const int wid = n >> 6, lane = n & 63;
  float r = 0.f, S = 0.f; int nb = 0;
  if (n < NNBR){
    nb = nbr[atom*NNBR + n];
    const float ax = pos[atom*3+0], ay = pos[atom*3+1], az = pos[atom*3+2];
    const int pi = (molBase + nb)*3;
    const float dx = pos[pi+0]-ax, dy = pos[pi+1]-ay, dz = pos[pi+2]-az;
    r = sqrtf(dx*dx + dy*dy + dz*dz + 1e-12f);
    const float m = mask[atom*NNBR + n];
    r *= m;
    const float C = (r < 5.0f) ? 0.5f*(__cosf(r*0.6283185307179586f)+1.0f) : 0.f;
    S = C * m;
  }
  r_c[atom*256 + n] = 0.f; S_c[atom*256 + n] = 0.f; nb_c[atom*256 + n] = 0;
  const unsigned long long b = __ballot(S != 0.f);
  const int rank = __popcll(b & ((1ull << lane) - 1ull));
  if (lane == 0) wcnt[wid] = __popcll(b);
  __syncthreads();
  int off = 0;
  for (int w = 0; w < 4; ++w) if (w < wid) off += wcnt[w];
  if (S != 0.f){
    const int slot = off + rank;
    r_c[atom*256 + slot] = r; S_c[atom*256 + slot] = S; nb_c[atom*256 + slot] = nb;
  }
  if (n == 0) nact_g[atom] = wcnt[0] + wcnt[1] + wcnt[2] + wcnt[3];
}

// ---- fw1/fw2 -> MFMA B-frags (bf16), parallel + coalesced.
__global__ void k_prepw(const float* __restrict__ fw1, const float* __restrict__ fw2,
                        unsigned short* __restrict__ b1f, unsigned short* __restrict__ b2f){
  const int i = blockIdx.x / 10, part = blockIdx.x % 10, tid = threadIdx.x;
  if (part < 2){
    const int e = part*256 + tid;                    // entry in [0,512)
    const float* w1 = fw1 + i*25*128;
    unsigned short* o1 = b1f + i*512*8;
    const int n = e >> 6, l = e & 63, khi = l >> 4, llo = l & 15;
    unsigned short v[8];
    #pragma unroll
    for (int j = 0; j < 8; ++j){
      const int g = khi*8 + j;
      v[j] = f2bf((g < 25) ? w1[g*128 + n*16 + llo] : 0.f);
    }
    *(float4*)(o1 + e*8) = *(float4*)v;
  } else {
    const int e = (part - 2)*256 + tid;              // entry in [0,2048)
    const float* w2 = fw2 + i*128*128;
    unsigned short* o2 = b2f + i*2048*8;
    const int frag = e >> 6, l = e & 63;
    const int k0 = frag >> 3, n = frag & 7, khi = l >> 4, llo = l & 15;
    unsigned short v[8];
    #pragma unroll
    for (int j = 0; j < 8; ++j){
      const int k = k0*32 + khi*8 + j;
      v[j] = f2bf(w2[k*128 + n*16 + llo]);
    }
    *(float4*)(o2 + e*8) = *(float4*)v;
  }
}

// ------------------------------------------ x = emb[Z]; y = x @ in2f_0
__global__ void k_init(const int* __restrict__ Z, const float* __restrict__ emb,
                       const float* __restrict__ in2f0,
                       float* __restrict__ x, float* __restrict__ y){
  __shared__ float xs[128];
  const int t = threadIdx.x;
  const int atom = (blockIdx.x & 7)*256 + (blockIdx.x >> 3);
  const float v = emb[Z[atom]*128 + t];
  x[atom*128 + t] = v; xs[t] = v;
  __syncthreads();
  float acc[8] = {0.f,0.f,0.f,0.f,0.f,0.f,0.f,0.f};
  #pragma unroll 4
  for (int d0 = 0; d0 < 128; d0 += 8)
    #pragma unroll
    for (int u = 0; u < 8; ++u)
      acc[u] = fmaf(xs[d0+u], in2f0[(d0+u)*128 + t], acc[u]);
  y[atom*128 + t] = ((acc[0]+acc[1])+(acc[2]+acc[3]))+((acc[4]+acc[5])+(acc[6]+acc[7]));
}

// ---- x += ssp(agg@f2out+b)@dense+b ; then y = x @ in2f_next (if given)
__global__ void k_mlp(const float* __restrict__ agg,
                      const float* __restrict__ f2w, const float* __restrict__ f2b,
                      const float* __restrict__ dw, const float* __restrict__ db,
                      const float* __restrict__ in2f_next,
                      float* __restrict__ x, float* __restrict__ y){
  __shared__ float aggL[128], v1[128], xs[128];
  const int t = threadIdx.x;
  const int atom = (blockIdx.x & 7)*256 + (blockIdx.x >> 3);
  aggL[t] = agg[atom*128 + t];
  __syncthreads();
  float a[8] = {0.f,0.f,0.f,0.f,0.f,0.f,0.f,0.f};
  #pragma unroll 4
  for (int d0 = 0; d0 < 128; d0 += 8)
    #pragma unroll
    for (int u = 0; u < 8; ++u)
      a[u] = fmaf(aggL[d0+u], f2w[(d0+u)*128 + t], a[u]);
  v1[t] = sspf(((a[0]+a[1])+(a[2]+a[3]))+((a[4]+a[5])+(a[6]+a[7])) + f2b[t]);
  __syncthreads();
  float b[8] = {0.f,0.f,0.f,0.f,0.f,0.f,0.f,0.f};
  #pragma unroll 4
  for (int d0 = 0; d0 < 128; d0 += 8)
    #pragma unroll
    for (int u = 0; u < 8; ++u)
      b[u] = fmaf(v1[d0+u], dw[(d0+u)*128 + t], b[u]);
  const float xn = x[atom*128 + t] +
      (((b[0]+b[1])+(b[2]+b[3]))+((b[4]+b[5])+(b[6]+b[7]))) + db[t];
  x[atom*128 + t] = xn;
  if (in2f_next){
    xs[t] = xn;
    __syncthreads();
    float yv[8] = {0.f,0.f,0.f,0.f,0.f,0.f,0.f,0.f};
    #pragma unroll 4
    for (int d0 = 0; d0 < 128; d0 += 8)
      #pragma unroll
      for (int u = 0; u < 8; ++u)
        yv[u] = fmaf(xs[d0+u], in2f_next[(d0+u)*128 + t], yv[u]);
    y[atom*128 + t] = ((yv[0]+yv[1])+(yv[2]+yv[3]))+((yv[4]+yv[5])+(yv[6]+yv[7]));
  }
}

// ---- filter net (MFMA) + cfconv agg: wave-per-atom, no staging, no barriers
__global__ __launch_bounds__(256, 4) void k_pairs(
    const float* __restrict__ r_c, const float* __restrict__ S_c,
    const int* __restrict__ nb_c, const int* __restrict__ nact_g,
    const float* __restrict__ y,
    const unsigned short* __restrict__ b1f, const unsigned short* __restrict__ b2f,
    const float* __restrict__ fb1, const float* __restrict__ fb2,
    float* __restrict__ agg){
  // LDS 16KB: 4 waves x 4KB wave-local swizzled H buffer
  __shared__ __align__(16) char smem[16384];
  const int tid = threadIdx.x;
  const int wid = tid >> 6, lane = tid & 63, lhi = lane >> 4, llo = lane & 15;
  const int mol = blockIdx.x & 7;                  // molecule == XCD
  const int atom = mol*256 + (blockIdx.x >> 3)*4 + wid, molBase = mol*256;
  char* Hw = smem + wid*4096;

  float b1b[8], b2b[8];
  #pragma unroll
  for (int n = 0; n < 8; ++n){ b1b[n] = fb1[n*16 + llo]; b2b[n] = fb2[n*16 + llo]; }

  const int nact = nact_g[atom];
  const int ntiles = (nact + 15) >> 4;

  float aggp[8];
  #pragma unroll
  for (int n = 0; n < 8; ++n) aggp[n] = 0.f;

  const float STEP = 5.0f/24.0f;
  const float GC   = -11.52f;              // -0.5/STEP^2

  for (int t = 0; t < ntiles; ++t){
    const int row0 = t*16;
    // A1 fragment in-register: f[row0+llo][g=8*lhi+jj]
    const float r = r_c[atom*256 + row0 + llo];
    bf16x8 a1;
    #pragma unroll
    for (int jj = 0; jj < 8; ++jj){
      const int g = lhi*8 + jj;
      float v = 0.f;
      if (g < 25){ const float d = r - (float)g*STEP; v = __expf(GC*d*d); }
      a1[jj] = (short)f2bf(v);
    }
    // GEMM1 (2 halves of 4 frags to bound VGPR): H = f @ fw1 + b1 (bias via C)
    #pragma unroll
    for (int half = 0; half < 2; ++half){
      f32x4 h[4];
      #pragma unroll
      for (int q = 0; q < 4; ++q){
        const int n = half*4 + q;
        const bf16x8 b1v = *(const bf16x8*)(b1f + (n*64 + lane)*8);
        const f32x4 cin = {b1b[n], b1b[n], b1b[n], b1b[n]};
        h[q] = __builtin_amdgcn_mfma_f32_16x16x32_bf16(a1, b1v, cin, 0, 0, 0);
      }
      // ssp -> bf16 into wave-local swizzled LDS (transpose for GEMM2 A-frag)
      #pragma unroll
      for (int q = 0; q < 4; ++q){
        const int n = half*4 + q;
        #pragma unroll
        for (int j = 0; j < 4; ++j){
          const int lrow = 4*lhi + j;
          const float hv = sspf(h[q][j]);
          const int boff = (lrow*256 + (n*16 + llo)*2) ^ ((lrow & 7) << 4);
          *(unsigned short*)(Hw + boff) = f2bf(hv);
        }
      }
    }
    // GEMM2: W = H @ fw2 + b2 (bias via C), K=128 in 4 steps, B from global/L1
    f32x4 acc[8];
    #pragma unroll
    for (int n = 0; n < 8; ++n) acc[n] = f32x4{b2b[n], b2b[n], b2b[n], b2b[n]};
    #pragma unroll
    for (int k0 = 0; k0 < 4; ++k0){
      const int boff = (llo*256 + k0*64 + lhi*16) ^ ((llo & 7) << 4);
      const bf16x8 a2 = *(const bf16x8*)(Hw + boff);
      #pragma unroll
      for (int n = 0; n < 8; ++n){
        const bf16x8 b2v = *(const bf16x8*)(b2f + ((k0*8 + n)*64 + lane)*8);
        acc[n] = __builtin_amdgcn_mfma_f32_16x16x32_bf16(a2, b2v, acc[n], 0, 0, 0);
      }
    }
    // aggregate: agg[f] += W*S * y[nbr]
    #pragma unroll
    for (int j = 0; j < 4; ++j){
      const int grow = row0 + 4*lhi + j;
      const float S = S_c[atom*256 + grow];
      const float* yrow = y + (molBase + nb_c[atom*256 + grow])*128;
      #pragma unroll
      for (int n = 0; n < 8; ++n)
        aggp[n] = fmaf(acc[n][j] * S, yrow[n*16 + llo], aggp[n]);
    }
  }

  // wave-local reduction across the 4 row-groups (lanes l, l^16, l^32, l^48)
  #pragma unroll
  for (int n = 0; n < 8; ++n){
    aggp[n] += __shfl_xor(aggp[n], 16);
    aggp[n] += __shfl_xor(aggp[n], 32);
  }
  if (lane < 16){
    #pragma unroll
    for (int n = 0; n < 8; ++n) agg[atom*128 + n*16 + lane] = aggp[n];
  }
}

// ---------------------------------------------------------------------------
extern "C" void kernel_launch(void* const* d_in, const int* in_sizes, int n_in,
                              void* d_out, int out_size, void* d_ws, size_t ws_size,
                              hipStream_t stream){
  const int*   Z    = (const int*)  d_in[0];
  const float* pos  = (const float*)d_in[1];
  const int*   nbr  = (const int*)  d_in[2];
  const float* mask = (const float*)d_in[3];
  const float* emb  = (const float*)d_in[4];
  const float* fw1  = (const float*)d_in[5];
  const float* fb1  = (const float*)d_in[6];
  const float* fw2  = (const float*)d_in[7];
  const float* fb2  = (const float*)d_in[8];
  const float* in2f = (const float*)d_in[9];
  const float* f2w  = (const float*)d_in[10];
  const float* f2b  = (const float*)d_in[11];
  const float* dw   = (const float*)d_in[12];
  const float* db   = (const float*)d_in[13];
  float* x = (float*)d_out;

  char* ws = (char*)d_ws;
  float* y    = (float*)ws;                               // 1MB
  float* agg  = (float*)(ws + 1*1024*1024);               // 1MB
  float* r_c  = (float*)(ws + 2*1024*1024);               // 2MB
  float* S_c  = (float*)(ws + 4*1024*1024);               // 2MB
  int*   nb_c = (int*)  (ws + 6*1024*1024);               // 2MB
  int*   nact = (int*)  (ws + 8*1024*1024);               // 8KB
  unsigned short* b1f = (unsigned short*)(ws + 8*1024*1024 + 16*1024);   // 24KB
  unsigned short* b2f = (unsigned short*)(ws + 8*1024*1024 + 64*1024);   // 96KB

  k_prepw<<<30,    256, 0, stream>>>(fw1, fw2, b1f, b2f);
  k_prep <<<NATOM, 256, 0, stream>>>(pos, nbr, mask, r_c, S_c, nb_c, nact);
  k_init <<<NATOM, 128, 0, stream>>>(Z, emb, in2f, x, y);
  for (int i = 0; i < 3; ++i){
    k_pairs<<<NATOM/4, 256, 0, stream>>>(r_c, S_c, nb_c, nact, y,
        b1f + i*512*8, b2f + i*2048*8, fb1 + i*128, fb2 + i*128, agg);
    k_mlp  <<<NATOM, 128, 0, stream>>>(agg,
        f2w + i*16384, f2b + i*128, dw + i*16384, db + i*128,
        (i < 2) ? (in2f + (i+1)*16384) : nullptr, x, y);
  }
}

// Round 7
// 180.676 us; speedup vs baseline: 6.4272x; 3.4097x over previous
//
#include <hip/hip_runtime.h>

// SchNet forward, MI355X. B=8,A=256,N=255,NB=NF=128,NG=25,NI=3,CUTOFF=5.
// R7: launch_bounds(256,2) ONLY (hints >=3 min-waves forced VGPR<=64 + 250MB
//     scratch spill in R4-R6); LDS-staged B2 frags (proven 7.7MB fetch in R2);
//     B1 frags in registers; 2 waves/atom; per-XCD weight copies.

#define NATOM 2048   // B*A
#define NNBR  255

typedef __attribute__((ext_vector_type(8))) short bf16x8;  // 8 bf16 = 4 VGPR
typedef __attribute__((ext_vector_type(4))) float f32x4;

__device__ __forceinline__ unsigned short f2bf(float x){
  unsigned int u = __float_as_uint(x);
  u += 0x7fffu + ((u >> 16) & 1u);            // round-to-nearest-even
  return (unsigned short)(u >> 16);
}

// ssp(x) = softplus(x) - ln2 = ln(0.5*e^x + 0.5)
__device__ __forceinline__ float sspf(float x){
  return __logf(fmaf(0.5f, __expf(x), 0.5f));
}

// ---------- geometry + deterministic compaction of active (S!=0) neighbors
__global__ void k_prep(const float* __restrict__ pos, const int* __restrict__ nbr,
                       const float* __restrict__ mask,
                       float* __restrict__ r_c, float* __restrict__ S_c,
                       int* __restrict__ nb_c, int* __restrict__ nact_g){
  __shared__ int wcnt[4];
  const int n = threadIdx.x;
  const int atom = (blockIdx.x & 7)*256 + (blockIdx.x >> 3);   // mol == XCD
  const int molBase = atom & ~255;
  const int wid = n >> 6, lane = n & 63;
  float r = 0.f, S = 0.f; int nb = 0;
  if (n < NNBR){
    nb = nbr[atom*NNBR + n];
    const float ax = pos[atom*3+0], ay = pos[atom*3+1], az = pos[atom*3+2];
    const int pi = (molBase + nb)*3;
    const float dx = pos[pi+0]-ax, dy = pos[pi+1]-ay, dz = pos[pi+2]-az;
    r = sqrtf(dx*dx + dy*dy + dz*dz + 1e-12f);
    const float m = mask[atom*NNBR + n];
    r *= m;
    const float C = (r < 5.0f) ? 0.5f*(__cosf(r*0.6283185307179586f)+1.0f) : 0.f;
    S = C * m;
  }
  r_c[atom*256 + n] = 0.f; S_c[atom*256 + n] = 0.f; nb_c[atom*256 + n] = 0;
  const unsigned long long b = __ballot(S != 0.f);
  const int rank = __popcll(b & ((1ull << lane) - 1ull));
  if (lane == 0) wcnt[wid] = __popcll(b);
  __syncthreads();
  int off = 0;
  for (int w = 0; w < 4; ++w) if (w < wid) off += wcnt[w];
  if (S != 0.f){
    const int slot = off + rank;
    r_c[atom*256 + slot] = r; S_c[atom*256 + slot] = S; nb_c[atom*256 + slot] = nb;
  }
  if (n == 0) nact_g[atom] = wcnt[0] + wcnt[1] + wcnt[2] + wcnt[3];
}

// ---- fw1/fw2 -> MFMA B-frags (bf16), 8 per-XCD copies, coalesced.
// Layout: b1f[(copy*3 + i)*4096 + e*8 + j], b2f[(copy*3 + i)*16384 + e*8 + j]
__global__ void k_prepw(const float* __restrict__ fw1, const float* __restrict__ fw2,
                        unsigned short* __restrict__ b1f, unsigned short* __restrict__ b2f){
  const int i = blockIdx.x / 10, part = blockIdx.x % 10, tid = threadIdx.x;
  if (part < 2){
    const int e = part*256 + tid;                    // entry in [0,512)
    const float* w1 = fw1 + i*25*128;
    unsigned short* o1 = b1f + i*4096;
    const int n = e >> 6, l = e & 63, khi = l >> 4, llo = l & 15;
    unsigned short v[8];
    #pragma unroll
    for (int j = 0; j < 8; ++j){
      const int g = khi*8 + j;
      v[j] = f2bf((g < 25) ? w1[g*128 + n*16 + llo] : 0.f);
    }
    #pragma unroll
    for (int c = 0; c < 8; ++c)
      *(float4*)(o1 + c*12288 + e*8) = *(float4*)v;
  } else {
    const int e = (part - 2)*256 + tid;              // entry in [0,2048)
    const float* w2 = fw2 + i*128*128;
    unsigned short* o2 = b2f + i*16384;
    const int frag = e >> 6, l = e & 63;
    const int k0 = frag >> 3, n = frag & 7, khi = l >> 4, llo = l & 15;
    unsigned short v[8];
    #pragma unroll
    for (int j = 0; j < 8; ++j){
      const int k = k0*32 + khi*8 + j;
      v[j] = f2bf(w2[k*128 + n*16 + llo]);
    }
    #pragma unroll
    for (int c = 0; c < 8; ++c)
      *(float4*)(o2 + c*49152 + e*8) = *(float4*)v;
  }
}

// ------------------------------------------ x = emb[Z]; y = x @ in2f_0
__global__ void k_init(const int* __restrict__ Z, const float* __restrict__ emb,
                       const float* __restrict__ in2f0,
                       float* __restrict__ x, float* __restrict__ y){
  __shared__ float xs[128];
  const int t = threadIdx.x;
  const int atom = (blockIdx.x & 7)*256 + (blockIdx.x >> 3);
  const float v = emb[Z[atom]*128 + t];
  x[atom*128 + t] = v; xs[t] = v;
  __syncthreads();
  float acc[8] = {0.f,0.f,0.f,0.f,0.f,0.f,0.f,0.f};
  #pragma unroll 4
  for (int d0 = 0; d0 < 128; d0 += 8)
    #pragma unroll
    for (int u = 0; u < 8; ++u)
      acc[u] = fmaf(xs[d0+u], in2f0[(d0+u)*128 + t], acc[u]);
  y[atom*128 + t] = ((acc[0]+acc[1])+(acc[2]+acc[3]))+((acc[4]+acc[5])+(acc[6]+acc[7]));
}

// ---- x += ssp(agg@f2out+b)@dense+b ; then y = x @ in2f_next (if given)
__global__ void k_mlp(const float* __restrict__ agg,
                      const float* __restrict__ f2w, const float* __restrict__ f2b,
                      const float* __restrict__ dw, const float* __restrict__ db,
                      const float* __restrict__ in2f_next,
                      float* __restrict__ x, float* __restrict__ y){
  __shared__ float aggL[128], v1[128], xs[128];
  const int t = threadIdx.x;
  const int atom = (blockIdx.x & 7)*256 + (blockIdx.x >> 3);
  aggL[t] = agg[atom*128 + t];
  __syncthreads();
  float a[8] = {0.f,0.f,0.f,0.f,0.f,0.f,0.f,0.f};
  #pragma unroll 4
  for (int d0 = 0; d0 < 128; d0 += 8)
    #pragma unroll
    for (int u = 0; u < 8; ++u)
      a[u] = fmaf(aggL[d0+u], f2w[(d0+u)*128 + t], a[u]);
  v1[t] = sspf(((a[0]+a[1])+(a[2]+a[3]))+((a[4]+a[5])+(a[6]+a[7])) + f2b[t]);
  __syncthreads();
  float b[8] = {0.f,0.f,0.f,0.f,0.f,0.f,0.f,0.f};
  #pragma unroll 4
  for (int d0 = 0; d0 < 128; d0 += 8)
    #pragma unroll
    for (int u = 0; u < 8; ++u)
      b[u] = fmaf(v1[d0+u], dw[(d0+u)*128 + t], b[u]);
  const float xn = x[atom*128 + t] +
      (((b[0]+b[1])+(b[2]+b[3]))+((b[4]+b[5])+(b[6]+b[7]))) + db[t];
  x[atom*128 + t] = xn;
  if (in2f_next){
    xs[t] = xn;
    __syncthreads();
    float yv[8] = {0.f,0.f,0.f,0.f,0.f,0.f,0.f,0.f};
    #pragma unroll 4
    for (int d0 = 0; d0 < 128; d0 += 8)
      #pragma unroll
      for (int u = 0; u < 8; ++u)
        yv[u] = fmaf(xs[d0+u], in2f_next[(d0+u)*128 + t], yv[u]);
    y[atom*128 + t] = ((yv[0]+yv[1])+(yv[2]+yv[3]))+((yv[4]+yv[5])+(yv[6]+yv[7]));
  }
}

// ---- filter net (MFMA) + cfconv agg: 2 atoms/block, 2 waves/atom, LDS B2
__global__ __launch_bounds__(256, 2) void k_pairs(
    const float* __restrict__ r_c, const float* __restrict__ S_c,
    const int* __restrict__ nb_c, const int* __restrict__ nact_g,
    const float* __restrict__ y,
    const unsigned short* __restrict__ b1f_i, const unsigned short* __restrict__ b2f_i,
    const float* __restrict__ fb1, const float* __restrict__ fb2,
    float* __restrict__ agg){
  // LDS 48KB: [0,32K) B2s staged once; [32K,48K) 4x4KB wave-local Hw
  __shared__ __align__(16) char smem[49152];
  unsigned short* B2s = (unsigned short*)smem;

  const int tid = threadIdx.x;
  const int wid = tid >> 6, lane = tid & 63, lhi = lane >> 4, llo = lane & 15;
  const int sub = wid & 1, ai = wid >> 1;          // 2 waves/atom, 2 atoms/block
  const int mol = blockIdx.x & 7;                  // molecule == XCD (heuristic)
  const int atom = mol*256 + (blockIdx.x >> 3)*2 + ai, molBase = mol*256;
  char* Hw = smem + 32768 + wid*4096;

  { // B2 fragments -> LDS from this XCD's weight copy (coalesced 32KB)
    const float4* src = (const float4*)(b2f_i + (size_t)mol*49152);
    float4* dst = (float4*)B2s;
    #pragma unroll
    for (int k = 0; k < 8; ++k) dst[k*256 + tid] = src[k*256 + tid];
  }
  // B1 fragments in registers (32 VGPR) from this XCD's copy
  bf16x8 B1[8];
  #pragma unroll
  for (int n = 0; n < 8; ++n)
    B1[n] = *(const bf16x8*)(b1f_i + (size_t)mol*12288 + (n*64 + lane)*8);
  float b1b[8], b2b[8];
  #pragma unroll
  for (int n = 0; n < 8; ++n){ b1b[n] = fb1[n*16 + llo]; b2b[n] = fb2[n*16 + llo]; }

  const int nact = nact_g[atom];
  const int ntiles = (nact + 15) >> 4;

  float aggp[8];
  #pragma unroll
  for (int n = 0; n < 8; ++n) aggp[n] = 0.f;

  const float STEP = 5.0f/24.0f;
  const float GC   = -11.52f;              // -0.5/STEP^2

  __syncthreads();                         // B2s ready

  for (int t = sub; t < ntiles; t += 2){
    const int row0 = t*16;
    // A1 fragment in-register: f[row0+llo][g=8*lhi+jj]
    const float r = r_c[atom*256 + row0 + llo];
    bf16x8 a1;
    #pragma unroll
    for (int jj = 0; jj < 8; ++jj){
      const int g = lhi*8 + jj;
      float v = 0.f;
      if (g < 25){ const float d = r - (float)g*STEP; v = __expf(GC*d*d); }
      a1[jj] = (short)f2bf(v);
    }
    // GEMM1: H = f @ fw1 + b1 (bias via MFMA C operand)
    f32x4 h[8];
    #pragma unroll
    for (int n = 0; n < 8; ++n){
      const f32x4 cin = {b1b[n], b1b[n], b1b[n], b1b[n]};
      h[n] = __builtin_amdgcn_mfma_f32_16x16x32_bf16(a1, B1[n], cin, 0, 0, 0);
    }
    // ssp -> bf16 into wave-local swizzled LDS (transpose for GEMM2 A-frag)
    #pragma unroll
    for (int n = 0; n < 8; ++n)
      #pragma unroll
      for (int j = 0; j < 4; ++j){
        const int lrow = 4*lhi + j;
        const float hv = sspf(h[n][j]);
        const int boff = (lrow*256 + (n*16 + llo)*2) ^ ((lrow & 7) << 4);
        *(unsigned short*)(Hw + boff) = f2bf(hv);
      }
    // GEMM2: W = H @ fw2 + b2 (bias via C), K=128 in 4 steps, B from LDS
    f32x4 acc[8];
    #pragma unroll
    for (int n = 0; n < 8; ++n) acc[n] = f32x4{b2b[n], b2b[n], b2b[n], b2b[n]};
    #pragma unroll
    for (int k0 = 0; k0 < 4; ++k0){
      const int boff = (llo*256 + k0*64 + lhi*16) ^ ((llo & 7) << 4);
      const bf16x8 a2 = *(const bf16x8*)(Hw + boff);
      #pragma unroll
      for (int n = 0; n < 8; ++n){
        const bf16x8 b2v = *(const bf16x8*)(B2s + ((k0*8 + n)*64 + lane)*8);
        acc[n] = __builtin_amdgcn_mfma_f32_16x16x32_bf16(a2, b2v, acc[n], 0, 0, 0);
      }
    }
    // aggregate: agg[f] += W*S * y[nbr]
    #pragma unroll
    for (int j = 0; j < 4; ++j){
      const int grow = row0 + 4*lhi + j;
      const float S = S_c[atom*256 + grow];
      const float* yrow = y + (molBase + nb_c[atom*256 + grow])*128;
      #pragma unroll
      for (int n = 0; n < 8; ++n)
        aggp[n] = fmaf(acc[n][j] * S, yrow[n*16 + llo], aggp[n]);
    }
  }

  // wave-local reduction across the 4 row-groups (lanes l, l^16, l^32, l^48)
  #pragma unroll
  for (int n = 0; n < 8; ++n){
    aggp[n] += __shfl_xor(aggp[n], 16);
    aggp[n] += __shfl_xor(aggp[n], 32);
  }
  // cross-wave (2 waves/atom) via per-wave LDS areas
  float* red = (float*)Hw;
  if (lane < 16){
    #pragma unroll
    for (int n = 0; n < 8; ++n) red[n*16 + lane] = aggp[n];
  }
  __syncthreads();
  if (sub == 0 && lane < 16){
    const float* red1 = (const float*)(smem + 32768 + (wid + 1)*4096);
    #pragma unroll
    for (int n = 0; n < 8; ++n)
      agg[atom*128 + n*16 + lane] = red[n*16 + lane] + red1[n*16 + lane];
  }
}

// ---------------------------------------------------------------------------
extern "C" void kernel_launch(void* const* d_in, const int* in_sizes, int n_in,
                              void* d_out, int out_size, void* d_ws, size_t ws_size,
                              hipStream_t stream){
  const int*   Z    = (const int*)  d_in[0];
  const float* pos  = (const float*)d_in[1];
  const int*   nbr  = (const int*)  d_in[2];
  const float* mask = (const float*)d_in[3];
  const float* emb  = (const float*)d_in[4];
  const float* fw1  = (const float*)d_in[5];
  const float* fb1  = (const float*)d_in[6];
  const float* fw2  = (const float*)d_in[7];
  const float* fb2  = (const float*)d_in[8];
  const float* in2f = (const float*)d_in[9];
  const float* f2w  = (const float*)d_in[10];
  const float* f2b  = (const float*)d_in[11];
  const float* dw   = (const float*)d_in[12];
  const float* db   = (const float*)d_in[13];
  float* x = (float*)d_out;

  char* ws = (char*)d_ws;
  float* y    = (float*)ws;                               // 1MB
  float* agg  = (float*)(ws + 1*1024*1024);               // 1MB
  float* r_c  = (float*)(ws + 2*1024*1024);               // 2MB
  float* S_c  = (float*)(ws + 4*1024*1024);               // 2MB
  int*   nb_c = (int*)  (ws + 6*1024*1024);               // 2MB
  int*   nact = (int*)  (ws + 8*1024*1024);               // 8KB
  unsigned short* b1f = (unsigned short*)(ws + 8*1024*1024 + 16*1024);   // 8x3x4096x2B = 196KB
  unsigned short* b2f = (unsigned short*)(ws + 8*1024*1024 + 256*1024);  // 8x3x16384x2B = 786KB

  k_prepw<<<30,    256, 0, stream>>>(fw1, fw2, b1f, b2f);
  k_prep <<<NATOM, 256, 0, stream>>>(pos, nbr, mask, r_c, S_c, nb_c, nact);
  k_init <<<NATOM, 128, 0, stream>>>(Z, emb, in2f, x, y);
  for (int i = 0; i < 3; ++i){
    k_pairs<<<NATOM/2, 256, 0, stream>>>(r_c, S_c, nb_c, nact, y,
        b1f + i*4096, b2f + i*16384, fb1 + i*128, fb2 + i*128, agg);
    k_mlp  <<<NATOM, 128, 0, stream>>>(agg,
        f2w + i*16384, f2b + i*128, dw + i*16384, db + i*128,
        (i < 2) ? (in2f + (i+1)*16384) : nullptr, x, y);
  }
}